// Round 10
// baseline (72.122 us; speedup 1.0000x reference)
//
#include <hip/hip_runtime.h>
#include <hip/hip_bf16.h>

// Problem constants (from reference setup)
#define HID   32
#define OUT   32
#define T_TOT 4096   // TRES*TRES
#define S_TOT 512    // B*NSUB

typedef __attribute__((ext_vector_type(8))) short short8;   // 8 bf16 = 4 VGPRs (MFMA A/B frag)
typedef __attribute__((ext_vector_type(4))) float f32x4;    // MFMA C/D frag

__device__ __forceinline__ float gelu_exact(float x) {
    return 0.5f * x * (1.0f + erff(x * 0.70710678118654752440f));
}

__device__ __forceinline__ unsigned int f2bf_u(float x) {
    __hip_bfloat16 h = __float2bfloat16(x);
    unsigned short us = *reinterpret_cast<unsigned short*>(&h);
    return (unsigned int)us;
}

// ---------------------------------------------------------------------------
// Kernel 1: target-grid hidden activations g[t,c] = gelu(tgt_coords @ tw1 + tb1)
// stored as bf16, row-major [4096][32]  (R3 verbatim)
// ---------------------------------------------------------------------------
__global__ __launch_bounds__(256) void k_tgt_hidden(
    const float* __restrict__ tw1, const float* __restrict__ tb1,
    unsigned int* __restrict__ Gbf /* [4096][16] uint = [4096][32] bf16 */) {
    int t = blockIdx.x * 256 + threadIdx.x;
    if (t >= T_TOT) return;
    int i = t >> 6, j = t & 63;
    const double step = 0.25 / 63.0;
    float x = (float)(-0.125 + (double)j * step);
    float y = (float)(-0.125 + (double)i * step);
    unsigned int pk[16];
#pragma unroll
    for (int c2 = 0; c2 < 16; ++c2) {
        float z0 = fmaf(x, tw1[2 * c2],     fmaf(y, tw1[HID + 2 * c2],     tb1[2 * c2]));
        float z1 = fmaf(x, tw1[2 * c2 + 1], fmaf(y, tw1[HID + 2 * c2 + 1], tb1[2 * c2 + 1]));
        pk[c2] = f2bf_u(gelu_exact(z0)) | (f2bf_u(gelu_exact(z1)) << 16);
    }
    uint4* dst = (uint4*)(Gbf + (size_t)t * 16);
#pragma unroll
    for (int k = 0; k < 4; ++k)
        dst[k] = make_uint4(pk[4 * k], pk[4 * k + 1], pk[4 * k + 2], pk[4 * k + 3]);
}

// ---------------------------------------------------------------------------
// Kernel 2 (fused): 512 blocks x 256 threads. Block s:
//   (1) R9's segment prologue VERBATIM -> writes Pbf[s] (bf16), qout[s] (f32)
//       to GLOBAL memory (the transport every passing kernel used; the LDS
//       handoff used by the two failed fusions is eliminated entirely).
//   (2) __threadfence_block + __syncthreads (vmcnt(0) drain before barrier).
//   (3) R7's contract loop VERBATIM: reads back its OWN Pbf[s]/qout[s]
//       (same-block global RAW through L2 — no cross-block dependency),
//       stores u[s] (4 waves x 64 tiles, dwordx4).
// G comes from k_tgt_hidden (prior kernel). No grid-wide sync needed.
// ---------------------------------------------------------------------------
__global__ __launch_bounds__(256) void k_all(
    const float* __restrict__ v, const float* __restrict__ coords,
    const float* __restrict__ sw1, const float* __restrict__ sb1,
    const float* __restrict__ sw2, const float* __restrict__ sb2,
    const float* __restrict__ tw2, const float* __restrict__ tb2,
    const unsigned short* __restrict__ Gbf,
    unsigned short* __restrict__ Pbf, float* __restrict__ qout,
    float* __restrict__ u) {
    const int s = blockIdx.x;
    const int b = s >> 6, cy = (s >> 3) & 7, cx = s & 7;
    const int tid = threadIdx.x;

    __shared__ float Hs[64][HID];
    __shared__ float Vs[64][HID];
    __shared__ float Ms[HID][HID];
    __shared__ float Vsum[HID];

    // ---- phase 0: load V + compute H (R9 verbatim) ----
    {
        int r = tid >> 2, qq = tid & 3;
        int p = b * 4096 + (cy * 8 + (r >> 3)) * 64 + cx * 8 + (r & 7);
        const f32x4* src = (const f32x4*)(v + (size_t)p * HID + qq * 8);
        f32x4 a0 = src[0], a1 = src[1];
        *(f32x4*)&Vs[r][qq * 8]     = a0;
        *(f32x4*)&Vs[r][qq * 8 + 4] = a1;

        float x = coords[2 * p], y = coords[2 * p + 1];
#pragma unroll
        for (int e = 0; e < 8; ++e) {
            int c = qq * 8 + e;
            float z = fmaf(x, sw1[c], fmaf(y, sw1[HID + c], sb1[c]));
            Hs[r][c] = gelu_exact(z);
        }
    }
    __syncthreads();

    // ---- M phase (R9 verbatim: c-pair threads 0..127, Vsum 128..159) ----
    if (tid < 128) {
        int cp = tid >> 3, hq = tid & 7;
        int c0 = cp * 2;
        f32x4 accA = {0.f, 0.f, 0.f, 0.f};
        f32x4 accB = {0.f, 0.f, 0.f, 0.f};
#pragma unroll 16
        for (int r = 0; r < 64; ++r) {
            float2 hv = *(const float2*)&Hs[r][c0];          // ds_read_b64
            f32x4 vv = *(const f32x4*)&Vs[r][hq * 4];        // ds_read_b128
            accA[0] = fmaf(hv.x, vv[0], accA[0]);
            accA[1] = fmaf(hv.x, vv[1], accA[1]);
            accA[2] = fmaf(hv.x, vv[2], accA[2]);
            accA[3] = fmaf(hv.x, vv[3], accA[3]);
            accB[0] = fmaf(hv.y, vv[0], accB[0]);
            accB[1] = fmaf(hv.y, vv[1], accB[1]);
            accB[2] = fmaf(hv.y, vv[2], accB[2]);
            accB[3] = fmaf(hv.y, vv[3], accB[3]);
        }
        *(f32x4*)&Ms[c0][hq * 4]     = accA;
        *(f32x4*)&Ms[c0 + 1][hq * 4] = accB;
    } else if (tid < 160) {
        int h = tid - 128;
        float sum = 0.f;
#pragma unroll 16
        for (int r = 0; r < 64; ++r) sum += Vs[r][h];
        Vsum[h] = sum;
    }
    __syncthreads();

    // ---- A+P merged (R9 verbatim; writes P/q to GLOBAL) ----
    {
        int o = tid >> 3, hq = tid & 7;
        f32x4 acc = {0.f, 0.f, 0.f, 0.f};
#pragma unroll 8
        for (int c = 0; c < HID; ++c) {
            f32x4 w = *(const f32x4*)(sw2 + (size_t)c * 1024 + o * 32 + hq * 4);
            f32x4 m = *(const f32x4*)&Ms[c][hq * 4];
            acc[0] = fmaf(m[0], w[0], acc[0]);
            acc[1] = fmaf(m[1], w[1], acc[1]);
            acc[2] = fmaf(m[2], w[2], acc[2]);
            acc[3] = fmaf(m[3], w[3], acc[3]);
        }
        f32x4 bb = *(const f32x4*)(sb2 + o * 32 + hq * 4);
        f32x4 vs = *(const f32x4*)&Vsum[hq * 4];
        acc[0] = fmaf(bb[0], vs[0], acc[0]);
        acc[1] = fmaf(bb[1], vs[1], acc[1]);
        acc[2] = fmaf(bb[2], vs[2], acc[2]);
        acc[3] = fmaf(bb[3], vs[3], acc[3]);
        const float inv = 1.0f / 64.0f;
        acc[0] *= inv; acc[1] *= inv; acc[2] *= inv; acc[3] *= inv;

        // gather A[o][*] from the 8 lanes of this o-group (same wave)
        f32x4 a[8];
        int base = (o & 7) * 8;
#pragma unroll
        for (int k = 0; k < 8; ++k) {
            a[k][0] = __shfl(acc[0], base + k, 64);
            a[k][1] = __shfl(acc[1], base + k, 64);
            a[k][2] = __shfl(acc[2], base + k, 64);
            a[k][3] = __shfl(acc[3], base + k, 64);
        }

        int cq = hq;
        unsigned int pk[2];
#pragma unroll
        for (int k2 = 0; k2 < 2; ++k2) {
            unsigned int w01 = 0;
#pragma unroll
            for (int kk = 0; kk < 2; ++kk) {
                int c = cq * 4 + k2 * 2 + kk;
                float pacc = 0.f;
#pragma unroll
                for (int h8 = 0; h8 < 8; ++h8) {
                    f32x4 w = *(const f32x4*)(tw2 + (size_t)c * 1024 + o * 32 + h8 * 4);
                    pacc = fmaf(w[0], a[h8][0], pacc);
                    pacc = fmaf(w[1], a[h8][1], pacc);
                    pacc = fmaf(w[2], a[h8][2], pacc);
                    pacc = fmaf(w[3], a[h8][3], pacc);
                }
                w01 |= f2bf_u(pacc) << (16 * kk);
            }
            pk[k2] = w01;
        }
        uint2 val; val.x = pk[0]; val.y = pk[1];
        *(uint2*)(Pbf + (size_t)s * 1024 + o * 32 + cq * 4) = val;

        if (cq == 0) {
            float qacc = 0.f;
#pragma unroll
            for (int h8 = 0; h8 < 8; ++h8) {
                f32x4 tb = *(const f32x4*)(tb2 + o * 32 + h8 * 4);
                qacc = fmaf(tb[0], a[h8][0], qacc);
                qacc = fmaf(tb[1], a[h8][1], qacc);
                qacc = fmaf(tb[2], a[h8][2], qacc);
                qacc = fmaf(tb[3], a[h8][3], qacc);
            }
            qout[s * 32 + o] = qacc;
        }
    }

    // ---- handoff: drain this block's global writes, then barrier ----
    __threadfence_block();
    __syncthreads();

    // ---- contract phase (R7's k_contract body VERBATIM, s = blockIdx.x) ----
    const int lane = tid & 63;
    const int wave = tid >> 6;
    const int lo = lane & 15;       // A: m(o)-row | B: n(t)-col | D: col(t)
    const int lk = lane >> 4;       // k-chunk of 8 channels

    const unsigned short* pb = Pbf + (size_t)s * 1024;
    short8 p0 = *(const short8*)(pb + lo * 32 + lk * 8);
    short8 p1 = *(const short8*)(pb + (16 + lo) * 32 + lk * 8);

    f32x4 c0, c1;
#pragma unroll
    for (int j = 0; j < 4; ++j) {
        c0[j] = qout[s * 32 + lk * 4 + j];
        c1[j] = qout[s * 32 + 16 + lk * 4 + j];
    }

    const int tbase = wave * 1024;          // wave owns t in [wave*1024, +1024)
    float* ubase = u + (size_t)s * (T_TOT * 32);

#pragma unroll 4
    for (int tile = 0; tile < 64; ++tile) {
        int t0 = tbase + tile * 16;
        short8 gfrag = *(const short8*)(Gbf + (size_t)(t0 + lo) * 32 + lk * 8);
        f32x4 d0 = __builtin_amdgcn_mfma_f32_16x16x32_bf16(p0, gfrag, c0, 0, 0, 0);
        f32x4 d1 = __builtin_amdgcn_mfma_f32_16x16x32_bf16(p1, gfrag, c1, 0, 0, 0);
        float* up = ubase + (size_t)(t0 + lo) * 32;
        *(f32x4*)(up + lk * 4)      = d0;
        *(f32x4*)(up + 16 + lk * 4) = d1;
    }
}

// ---------------------------------------------------------------------------
extern "C" void kernel_launch(void* const* d_in, const int* in_sizes, int n_in,
                              void* d_out, int out_size, void* d_ws, size_t ws_size,
                              hipStream_t stream) {
    (void)in_sizes; (void)n_in; (void)out_size; (void)ws_size;
    const float* v       = (const float*)d_in[0];
    const float* scoords = (const float*)d_in[1];
    // d_in[2] = src_batch (implied by structure), d_in[3] = tgt_res (=64)
    const float* sw1 = (const float*)d_in[4];
    const float* sb1 = (const float*)d_in[5];
    const float* sw2 = (const float*)d_in[6];
    const float* sb2 = (const float*)d_in[7];
    const float* tw1 = (const float*)d_in[8];
    const float* tb1 = (const float*)d_in[9];
    const float* tw2 = (const float*)d_in[10];
    const float* tb2 = (const float*)d_in[11];
    float* u = (float*)d_out;

    char* ws = (char*)d_ws;
    unsigned int*   Gbf  = (unsigned int*)ws;                       // 4096*32*2   = 262144 B
    unsigned short* Pbf  = (unsigned short*)(ws + 262144);          // 512*1024*2  = 1048576 B
    float*          qbuf = (float*)(ws + 262144 + 1048576);         // 512*32*4    = 65536 B

    hipLaunchKernelGGL(k_tgt_hidden, dim3(16), dim3(256), 0, stream, tw1, tb1, Gbf);
    hipLaunchKernelGGL(k_all, dim3(S_TOT), dim3(256), 0, stream,
                       v, scoords, sw1, sb1, sw2, sb2, tw2, tb2,
                       (const unsigned short*)Gbf, Pbf, qbuf, u);
}

// Round 11
// 64.287 us; speedup vs baseline: 1.1219x; 1.1219x over previous
//
#include <hip/hip_runtime.h>
#include <hip/hip_bf16.h>

// Problem constants (from reference setup)
#define HID   32
#define OUT   32
#define T_TOT 4096   // TRES*TRES
#define S_TOT 512    // B*NSUB

typedef __attribute__((ext_vector_type(8))) short short8;   // 8 bf16 = 4 VGPRs (MFMA A/B frag)
typedef __attribute__((ext_vector_type(4))) float f32x4;    // MFMA C/D frag

__device__ __forceinline__ float gelu_exact(float x) {
    return 0.5f * x * (1.0f + erff(x * 0.70710678118654752440f));
}

__device__ __forceinline__ unsigned int f2bf_u(float x) {
    __hip_bfloat16 h = __float2bfloat16(x);
    unsigned short us = *reinterpret_cast<unsigned short*>(&h);
    return (unsigned int)us;
}

// ---------------------------------------------------------------------------
// Kernel A: blocks 0..511 = per-segment pipeline; blocks 512..527 = G gen.
// vs R9: M-phase now uses ALL 4 waves (wave w owns r-chunk [16w,16w+16),
// lane = (cg,hq) computes a 4x4 (c,h) patch -> partial Mp[w]); Vsum split
// 8 ways; one extra reduce phase sums partials. A+P merged phase verbatim R9.
// ---------------------------------------------------------------------------
__global__ __launch_bounds__(256) void k_seg_G(
    const float* __restrict__ v, const float* __restrict__ coords,
    const float* __restrict__ sw1, const float* __restrict__ sb1,
    const float* __restrict__ sw2, const float* __restrict__ sb2,
    const float* __restrict__ tw2, const float* __restrict__ tb2,
    const float* __restrict__ tw1, const float* __restrict__ tb1,
    unsigned short* __restrict__ Pbf, float* __restrict__ qout,
    unsigned int* __restrict__ Gbf) {
    const int tid = threadIdx.x;

    // ---------------- G-generation blocks (R3's k_tgt_hidden, verbatim) ----
    if (blockIdx.x >= S_TOT) {
        int t = (blockIdx.x - S_TOT) * 256 + tid;
        int i = t >> 6, j = t & 63;
        const double step = 0.25 / 63.0;
        float x = (float)(-0.125 + (double)j * step);
        float y = (float)(-0.125 + (double)i * step);
        unsigned int pk[16];
#pragma unroll
        for (int c2 = 0; c2 < 16; ++c2) {
            float z0 = fmaf(x, tw1[2 * c2],     fmaf(y, tw1[HID + 2 * c2],     tb1[2 * c2]));
            float z1 = fmaf(x, tw1[2 * c2 + 1], fmaf(y, tw1[HID + 2 * c2 + 1], tb1[2 * c2 + 1]));
            pk[c2] = f2bf_u(gelu_exact(z0)) | (f2bf_u(gelu_exact(z1)) << 16);
        }
        uint4* dst = (uint4*)(Gbf + (size_t)t * 16);
#pragma unroll
        for (int k = 0; k < 4; ++k)
            dst[k] = make_uint4(pk[4 * k], pk[4 * k + 1], pk[4 * k + 2], pk[4 * k + 3]);
        return;
    }

    // ---------------- segment blocks ----------------
    const int s = blockIdx.x;
    const int b = s >> 6, cy = (s >> 3) & 7, cx = s & 7;

    __shared__ float Hs[64][HID];
    __shared__ float Vs[64][HID];
    __shared__ float Mp[4][HID][HID];   // per-r-chunk partial M
    __shared__ float Vsp[8][HID];       // per-r-chunk partial Vsum
    __shared__ float Ms[HID][HID];
    __shared__ float Vsum[HID];

    // ---- phase 0: load V + compute H (R9 verbatim) ----
    {
        int r = tid >> 2, qq = tid & 3;
        int p = b * 4096 + (cy * 8 + (r >> 3)) * 64 + cx * 8 + (r & 7);
        const f32x4* src = (const f32x4*)(v + (size_t)p * HID + qq * 8);
        f32x4 a0 = src[0], a1 = src[1];
        *(f32x4*)&Vs[r][qq * 8]     = a0;
        *(f32x4*)&Vs[r][qq * 8 + 4] = a1;

        float x = coords[2 * p], y = coords[2 * p + 1];
#pragma unroll
        for (int e = 0; e < 8; ++e) {
            int c = qq * 8 + e;
            float z = fmaf(x, sw1[c], fmaf(y, sw1[HID + c], sb1[c]));
            Hs[r][c] = gelu_exact(z);
        }
    }
    __syncthreads();

    // ---- M phase: all 4 waves. wave w: r in [16w,16w+16); lane (cg,hq)
    // computes 4x4 (c,h) patch into Mp[w]. Plus 8-way Vsum partials. ----
    {
        const int w  = tid >> 6;
        const int l  = tid & 63;
        const int hq = l & 7;
        const int cg = l >> 3;
        const int r0 = w * 16;
        f32x4 acc0 = {0.f, 0.f, 0.f, 0.f};
        f32x4 acc1 = {0.f, 0.f, 0.f, 0.f};
        f32x4 acc2 = {0.f, 0.f, 0.f, 0.f};
        f32x4 acc3 = {0.f, 0.f, 0.f, 0.f};
#pragma unroll
        for (int rr = 0; rr < 16; ++rr) {
            int r = r0 + rr;
            f32x4 hv = *(const f32x4*)&Hs[r][cg * 4];   // 4 c's
            f32x4 vv = *(const f32x4*)&Vs[r][hq * 4];   // 4 h's
            acc0[0] = fmaf(hv[0], vv[0], acc0[0]);
            acc0[1] = fmaf(hv[0], vv[1], acc0[1]);
            acc0[2] = fmaf(hv[0], vv[2], acc0[2]);
            acc0[3] = fmaf(hv[0], vv[3], acc0[3]);
            acc1[0] = fmaf(hv[1], vv[0], acc1[0]);
            acc1[1] = fmaf(hv[1], vv[1], acc1[1]);
            acc1[2] = fmaf(hv[1], vv[2], acc1[2]);
            acc1[3] = fmaf(hv[1], vv[3], acc1[3]);
            acc2[0] = fmaf(hv[2], vv[0], acc2[0]);
            acc2[1] = fmaf(hv[2], vv[1], acc2[1]);
            acc2[2] = fmaf(hv[2], vv[2], acc2[2]);
            acc2[3] = fmaf(hv[2], vv[3], acc2[3]);
            acc3[0] = fmaf(hv[3], vv[0], acc3[0]);
            acc3[1] = fmaf(hv[3], vv[1], acc3[1]);
            acc3[2] = fmaf(hv[3], vv[2], acc3[2]);
            acc3[3] = fmaf(hv[3], vv[3], acc3[3]);
        }
        *(f32x4*)&Mp[w][cg * 4 + 0][hq * 4] = acc0;
        *(f32x4*)&Mp[w][cg * 4 + 1][hq * 4] = acc1;
        *(f32x4*)&Mp[w][cg * 4 + 2][hq * 4] = acc2;
        *(f32x4*)&Mp[w][cg * 4 + 3][hq * 4] = acc3;

        int rc = tid >> 5, h = tid & 31;
        float sum = 0.f;
#pragma unroll
        for (int j = 0; j < 8; ++j) sum += Vs[rc * 8 + j][h];
        Vsp[rc][h] = sum;
    }
    __syncthreads();

    // ---- reduce phase: Ms = sum_w Mp[w]; Vsum = sum_rc Vsp[rc] ----
    {
        int c = tid >> 3, hq = tid & 7;
        f32x4 m0 = *(const f32x4*)&Mp[0][c][hq * 4];
        f32x4 m1 = *(const f32x4*)&Mp[1][c][hq * 4];
        f32x4 m2 = *(const f32x4*)&Mp[2][c][hq * 4];
        f32x4 m3 = *(const f32x4*)&Mp[3][c][hq * 4];
        f32x4 mm;
#pragma unroll
        for (int j = 0; j < 4; ++j) mm[j] = (m0[j] + m1[j]) + (m2[j] + m3[j]);
        *(f32x4*)&Ms[c][hq * 4] = mm;
        if (tid < 32) {
            float s2 = 0.f;
#pragma unroll
            for (int rc = 0; rc < 8; ++rc) s2 += Vsp[rc][tid];
            Vsum[tid] = s2;
        }
    }
    __syncthreads();

    // ---- A+P merged (R9 verbatim; writes P/q to GLOBAL) ----
    {
        int o = tid >> 3, hq = tid & 7;
        f32x4 acc = {0.f, 0.f, 0.f, 0.f};
#pragma unroll 8
        for (int c = 0; c < HID; ++c) {
            f32x4 w = *(const f32x4*)(sw2 + (size_t)c * 1024 + o * 32 + hq * 4);
            f32x4 m = *(const f32x4*)&Ms[c][hq * 4];
            acc[0] = fmaf(m[0], w[0], acc[0]);
            acc[1] = fmaf(m[1], w[1], acc[1]);
            acc[2] = fmaf(m[2], w[2], acc[2]);
            acc[3] = fmaf(m[3], w[3], acc[3]);
        }
        f32x4 bb = *(const f32x4*)(sb2 + o * 32 + hq * 4);
        f32x4 vs = *(const f32x4*)&Vsum[hq * 4];
        acc[0] = fmaf(bb[0], vs[0], acc[0]);
        acc[1] = fmaf(bb[1], vs[1], acc[1]);
        acc[2] = fmaf(bb[2], vs[2], acc[2]);
        acc[3] = fmaf(bb[3], vs[3], acc[3]);
        const float inv = 1.0f / 64.0f;
        acc[0] *= inv; acc[1] *= inv; acc[2] *= inv; acc[3] *= inv;

        // gather A[o][*] from the 8 lanes of this o-group (same wave)
        f32x4 a[8];
        int base = (o & 7) * 8;
#pragma unroll
        for (int k = 0; k < 8; ++k) {
            a[k][0] = __shfl(acc[0], base + k, 64);
            a[k][1] = __shfl(acc[1], base + k, 64);
            a[k][2] = __shfl(acc[2], base + k, 64);
            a[k][3] = __shfl(acc[3], base + k, 64);
        }

        int cq = hq;
        unsigned int pk[2];
#pragma unroll
        for (int k2 = 0; k2 < 2; ++k2) {
            unsigned int w01 = 0;
#pragma unroll
            for (int kk = 0; kk < 2; ++kk) {
                int c = cq * 4 + k2 * 2 + kk;
                float pacc = 0.f;
#pragma unroll
                for (int h8 = 0; h8 < 8; ++h8) {
                    f32x4 w = *(const f32x4*)(tw2 + (size_t)c * 1024 + o * 32 + h8 * 4);
                    pacc = fmaf(w[0], a[h8][0], pacc);
                    pacc = fmaf(w[1], a[h8][1], pacc);
                    pacc = fmaf(w[2], a[h8][2], pacc);
                    pacc = fmaf(w[3], a[h8][3], pacc);
                }
                w01 |= f2bf_u(pacc) << (16 * kk);
            }
            pk[k2] = w01;
        }
        uint2 val; val.x = pk[0]; val.y = pk[1];
        *(uint2*)(Pbf + (size_t)s * 1024 + o * 32 + cq * 4) = val;

        if (cq == 0) {
            float qacc = 0.f;
#pragma unroll
            for (int h8 = 0; h8 < 8; ++h8) {
                f32x4 tb = *(const f32x4*)(tb2 + o * 32 + h8 * 4);
                qacc = fmaf(tb[0], a[h8][0], qacc);
                qacc = fmaf(tb[1], a[h8][1], qacc);
                qacc = fmaf(tb[2], a[h8][2], qacc);
                qacc = fmaf(tb[3], a[h8][3], qacc);
            }
            qout[s * 32 + o] = qacc;
        }
    }
}

// ---------------------------------------------------------------------------
// Kernel B: u[s,t,o] = sum_c G[t,c]*P[s,o,c] + q[s,o] via MFMA 16x16x32 bf16.
// R9 verbatim (grid (4,512), dwordx4 stores; ~47 us = 84% of fill ceiling).
// ---------------------------------------------------------------------------
__global__ __launch_bounds__(256) void k_contract(
    const unsigned short* __restrict__ Gbf,
    const unsigned short* __restrict__ Pbf,
    const float* __restrict__ q,
    float* __restrict__ u) {
    const int s    = blockIdx.y;
    const int lane = threadIdx.x & 63;
    const int wave = threadIdx.x >> 6;
    const int lo = lane & 15;       // A: m(o)-row | B: n(t)-col | D: col(t)
    const int lk = lane >> 4;       // k-chunk of 8 channels

    const unsigned short* pb = Pbf + (size_t)s * 1024;
    short8 p0 = *(const short8*)(pb + lo * 32 + lk * 8);
    short8 p1 = *(const short8*)(pb + (16 + lo) * 32 + lk * 8);

    f32x4 c0, c1;
#pragma unroll
    for (int j = 0; j < 4; ++j) {
        c0[j] = q[s * 32 + lk * 4 + j];
        c1[j] = q[s * 32 + 16 + lk * 4 + j];
    }

    const int tbase = blockIdx.x * 1024 + wave * 256;
    float* ubase = u + (size_t)s * (T_TOT * 32);

#pragma unroll 4
    for (int tile = 0; tile < 16; ++tile) {
        int t0 = tbase + tile * 16;
        short8 gfrag = *(const short8*)(Gbf + (size_t)(t0 + lo) * 32 + lk * 8);
        f32x4 d0 = __builtin_amdgcn_mfma_f32_16x16x32_bf16(p0, gfrag, c0, 0, 0, 0);
        f32x4 d1 = __builtin_amdgcn_mfma_f32_16x16x32_bf16(p1, gfrag, c1, 0, 0, 0);
        float* up = ubase + (size_t)(t0 + lo) * 32;
        *(f32x4*)(up + lk * 4)      = d0;
        *(f32x4*)(up + 16 + lk * 4) = d1;
    }
}

// ---------------------------------------------------------------------------
extern "C" void kernel_launch(void* const* d_in, const int* in_sizes, int n_in,
                              void* d_out, int out_size, void* d_ws, size_t ws_size,
                              hipStream_t stream) {
    (void)in_sizes; (void)n_in; (void)out_size; (void)ws_size;
    const float* v       = (const float*)d_in[0];
    const float* scoords = (const float*)d_in[1];
    // d_in[2] = src_batch (implied by structure), d_in[3] = tgt_res (=64)
    const float* sw1 = (const float*)d_in[4];
    const float* sb1 = (const float*)d_in[5];
    const float* sw2 = (const float*)d_in[6];
    const float* sb2 = (const float*)d_in[7];
    const float* tw1 = (const float*)d_in[8];
    const float* tb1 = (const float*)d_in[9];
    const float* tw2 = (const float*)d_in[10];
    const float* tb2 = (const float*)d_in[11];
    float* u = (float*)d_out;

    char* ws = (char*)d_ws;
    unsigned int*   Gbf  = (unsigned int*)ws;                       // 4096*32*2   = 262144 B
    unsigned short* Pbf  = (unsigned short*)(ws + 262144);          // 512*1024*2  = 1048576 B
    float*          qbuf = (float*)(ws + 262144 + 1048576);         // 512*32*4    = 65536 B

    hipLaunchKernelGGL(k_seg_G, dim3(S_TOT + 16), dim3(256), 0, stream,
                       v, scoords, sw1, sb1, sw2, sb2, tw2, tb2, tw1, tb1,
                       Pbf, qbuf, Gbf);
    hipLaunchKernelGGL(k_contract, dim3(4, S_TOT), dim3(256), 0, stream,
                       (const unsigned short*)Gbf, (const unsigned short*)Pbf, qbuf, u);
}